// Round 12
// baseline (201.035 us; speedup 1.0000x reference)
//
#include <hip/hip_runtime.h>

#define D 128
#define C 40
#define NBH 256        // blocks participating in hist/partition (also their thread count)
#define BSH 8          // bucket = dst >> 8  (256 nodes per bucket)
#define NBKT_MAX 512
#define EPB 6272       // max edges per partition block (E/NBH=6250 rounded up)

typedef __attribute__((ext_vector_type(8))) short s8v;
typedef __attribute__((ext_vector_type(4))) float f4v;

// bf16 <-> f32 (raw ushort storage; f2bf = round-to-nearest-even)
__device__ __forceinline__ float bf2f(unsigned short u) {
    union { unsigned int i; float f; } v; v.i = ((unsigned int)u) << 16; return v.f;
}
__device__ __forceinline__ unsigned short f2bf(float f) {
    unsigned int x = __float_as_uint(f);
    unsigned int r = (x + 0x7FFFu + ((x >> 16) & 1u)) >> 16;
    return (unsigned short)r;
}

// ---- K1: merged LDS-histogram (256 blocks, chunked) || MFMA projection y0 = X W ----
// Proj writes PLANAR: cols 0..19 -> zlo (40B rows), cols 20..39 -> zhi.
__global__ void hist_proj_kernel(const int* __restrict__ dst, int* __restrict__ M, int E,
                                 const float* __restrict__ x, const float* __restrict__ W,
                                 unsigned short* __restrict__ zlo, unsigned short* __restrict__ zhi,
                                 int n, int nbkt) {
    __shared__ int shist[NBKT_MAX];      // 2 KB (hist role only)
    int bid = blockIdx.x, tid = threadIdx.x;
    int role, sub;  // role 1 = hist, 0 = proj
    if (bid < 2 * NBH) { role = bid & 1; sub = bid >> 1; }
    else { role = 0; sub = bid - NBH; }

    if (role == 1) {
        for (int t = tid; t < nbkt; t += 256) shist[t] = 0;
        __syncthreads();
        int chunk = (E + NBH - 1) / NBH;
        int base = sub * chunk;
        int lim = min(E, base + chunk);
        for (int e = base + tid; e < lim; e += 256)
            atomicAdd(&shist[dst[e] >> BSH], 1);
        __syncthreads();
        for (int t = tid; t < nbkt; t += 256) M[t * NBH + sub] = shist[t];
        return;
    }

    // ---- projection role: MFMA 16x16x32 bf16, 16 rows per wave, W in registers ----
    int wid = tid >> 6;
    int lane = tid & 63;
    int tile = sub * 4 + wid;               // 16-row tile (N % 16 == 0)
    if (tile * 16 >= n) return;
    int r = lane & 15;
    int kg = lane >> 4;                     // 0..3

    s8v bfrag[3][4];
#pragma unroll
    for (int ct = 0; ct < 3; ++ct) {
        int col = ct * 16 + r;
#pragma unroll
        for (int ks = 0; ks < 4; ++ks) {
            s8v f;
#pragma unroll
            for (int j = 0; j < 8; ++j) {
                int k = ks * 32 + kg * 8 + j;
                float wv = (col < C) ? W[k * C + col] : 0.0f;
                f[j] = (short)f2bf(wv);
            }
            bfrag[ct][ks] = f;
        }
    }

    f4v acc0 = {0.f, 0.f, 0.f, 0.f};
    f4v acc1 = {0.f, 0.f, 0.f, 0.f};
    f4v acc2 = {0.f, 0.f, 0.f, 0.f};
    int row = tile * 16 + r;
    const float4* xrow = (const float4*)(x + (size_t)row * D);
#pragma unroll
    for (int ks = 0; ks < 4; ++ks) {
        int kb = ks * 32 + kg * 8;
        float4 u0 = xrow[kb >> 2];
        float4 u1 = xrow[(kb >> 2) + 1];
        s8v af;
        af[0] = (short)f2bf(u0.x); af[1] = (short)f2bf(u0.y);
        af[2] = (short)f2bf(u0.z); af[3] = (short)f2bf(u0.w);
        af[4] = (short)f2bf(u1.x); af[5] = (short)f2bf(u1.y);
        af[6] = (short)f2bf(u1.z); af[7] = (short)f2bf(u1.w);
        acc0 = __builtin_amdgcn_mfma_f32_16x16x32_bf16(af, bfrag[0][ks], acc0, 0, 0, 0);
        acc1 = __builtin_amdgcn_mfma_f32_16x16x32_bf16(af, bfrag[1][ks], acc1, 0, 0, 0);
        acc2 = __builtin_amdgcn_mfma_f32_16x16x32_bf16(af, bfrag[2][ks], acc2, 0, 0, 0);
    }
    // D layout: col = lane&15, row_in_tile = kg*4 + reg. Planar write.
#pragma unroll
    for (int rg = 0; rg < 4; ++rg) {
        int orow = tile * 16 + kg * 4 + rg;
        unsigned short* lo = zlo + (size_t)orow * 20;
        unsigned short* hi = zhi + (size_t)orow * 20;
        lo[r] = f2bf(acc0[rg]);                  // cols 0..15
        if (r < 4) lo[16 + r] = f2bf(acc1[rg]);  // cols 16..19
        else       hi[r - 4]  = f2bf(acc1[rg]);  // cols 20..31
        if (r < 8) hi[12 + r] = f2bf(acc2[rg]);  // cols 32..39
    }
}

// ---- K2: exclusive-scan each bucket's row of M (per-block counts); emit totals ----
__global__ void scanM_kernel(int* __restrict__ M, int* __restrict__ btot, int nbkt) {
    __shared__ int s[NBH];
    int b = blockIdx.x, tid = threadIdx.x;
    int v = M[b * NBH + tid];
    s[tid] = v;
    __syncthreads();
    for (int off = 1; off < NBH; off <<= 1) {
        int t = (tid >= off) ? s[tid - off] : 0;
        __syncthreads();
        s[tid] += t;
        __syncthreads();
    }
    M[b * NBH + tid] = s[tid] - v;   // exclusive
    if (tid == NBH - 1) btot[b] = s[tid];
}

// ---- K3: exclusive-scan bucket totals -> bucketBase; seal rowptr[N] ----
__global__ void scanB_kernel(const int* __restrict__ btot, int* __restrict__ bbase,
                             int* __restrict__ rowptr, int nbkt, int n, int E) {
    __shared__ int s[512];
    int tid = threadIdx.x;
    int v = (tid < nbkt) ? btot[tid] : 0;
    s[tid] = v;
    __syncthreads();
    for (int off = 1; off < 512; off <<= 1) {
        int t = (tid >= off) ? s[tid - off] : 0;
        __syncthreads();
        s[tid] += t;
        __syncthreads();
    }
    if (tid < nbkt) bbase[tid] = s[tid] - v;
    if (tid == 0) { bbase[nbkt] = E; rowptr[n] = E; }
}

// ---- K4: partition via LDS counting sort -> coalesced bucket-run writes ----
__global__ void __launch_bounds__(256)
part_kernel(const int* __restrict__ src, const int* __restrict__ dst,
            const int* __restrict__ M, const int* __restrict__ bbase,
            int* __restrict__ ebuf, int E, int nbkt) {
    __shared__ int lhist[NBKT_MAX];
    __shared__ int ls[NBKT_MAX];
    __shared__ int lslot[NBKT_MAX];
    __shared__ int sdelta[NBKT_MAX];
    __shared__ int sVal[EPB];
    __shared__ int sG[EPB];
    int blk = blockIdx.x, tid = threadIdx.x;
    int chunk = (E + NBH - 1) / NBH;
    int base = blk * chunk;
    int lim = min(E, base + chunk);
    int cnt = lim - base;

    for (int t = tid; t < NBKT_MAX; t += 256) lhist[t] = 0;
    __syncthreads();
    for (int e = base + tid; e < lim; e += 256)
        atomicAdd(&lhist[dst[e] >> BSH], 1);
    __syncthreads();
    {
        int i0 = tid, i1 = tid + 256;
        ls[i0] = lhist[i0]; ls[i1] = lhist[i1];
        __syncthreads();
        for (int off = 1; off < 512; off <<= 1) {
            int v0 = (i0 >= off) ? ls[i0 - off] : 0;
            int v1 = (i1 >= off) ? ls[i1 - off] : 0;
            __syncthreads();
            ls[i0] += v0; ls[i1] += v1;
            __syncthreads();
        }
    }
    for (int t = tid; t < nbkt; t += 256) {
        int excl = ls[t] - lhist[t];
        lslot[t] = excl;
        sdelta[t] = bbase[t] + M[t * NBH + blk] - excl;
    }
    __syncthreads();
    for (int e = base + tid; e < lim; e += 256) {
        int d = dst[e];
        int t = d >> BSH;
        int slot = atomicAdd(&lslot[t], 1);
        sVal[slot] = src[e] | ((d & ((1 << BSH) - 1)) << 17);
        sG[slot] = sdelta[t] + slot;
    }
    __syncthreads();
    for (int i = tid; i < cnt; i += 256) ebuf[sG[i]] = sVal[i];
}

// ---- K5: per-bucket CSR build (hist, scan, rank in LDS) + z0 = dis*y0 (planar) ----
__global__ void bucket_csr_kernel(const int* __restrict__ ebuf, const int* __restrict__ bbase,
                                  int* __restrict__ rowptr, float* __restrict__ dis,
                                  int* __restrict__ srcs,
                                  unsigned short* __restrict__ zlo,
                                  unsigned short* __restrict__ zhi, int n) {
    __shared__ int scnt[256];
    __shared__ int s[256];
    __shared__ int sptr[256];
    __shared__ float sdis[256];
    int b = blockIdx.x, tid = threadIdx.x;
    int lo = bbase[b], hi = bbase[b + 1];
    scnt[tid] = 0;
    __syncthreads();
    for (int i = lo + tid; i < hi; i += 256)
        atomicAdd(&scnt[(ebuf[i] >> 17) & 255], 1);
    __syncthreads();
    int v = scnt[tid];
    s[tid] = v;
    __syncthreads();
    for (int off = 1; off < 256; off <<= 1) {
        int t = (tid >= off) ? s[tid - off] : 0;
        __syncthreads();
        s[tid] += t;
        __syncthreads();
    }
    int excl = s[tid] - v;
    int node = b * 256 + tid;
    float dv = rsqrtf(1.0f + (float)v);
    if (node < n) { rowptr[node] = lo + excl; dis[node] = dv; }
    sdis[tid] = dv;
    sptr[tid] = lo + excl;
    __syncthreads();
    for (int i = lo + tid; i < hi; i += 256) {
        int ev = ebuf[i];
        int pos = atomicAdd(&sptr[(ev >> 17) & 255], 1);
        srcs[pos] = ev & 0x1FFFF;
    }
    // epilogue: z0 = dis * y0 (both planes, 5 ushort4 per plane per node)
    __syncthreads();
    ushort4* lo4 = (ushort4*)zlo;
    ushort4* hi4 = (ushort4*)zhi;
    size_t base4 = (size_t)b * 256 * 5;
    for (int idx = tid; idx < 256 * 5; idx += 256) {
        int node2 = b * 256 + idx / 5;
        if (node2 < n) {
            float sc = sdis[idx / 5];
            ushort4 u = lo4[base4 + idx];
            u.x = f2bf(sc * bf2f(u.x)); u.y = f2bf(sc * bf2f(u.y));
            u.z = f2bf(sc * bf2f(u.z)); u.w = f2bf(sc * bf2f(u.w));
            lo4[base4 + idx] = u;
            ushort4 w = hi4[base4 + idx];
            w.x = f2bf(sc * bf2f(w.x)); w.y = f2bf(sc * bf2f(w.y));
            w.z = f2bf(sc * bf2f(w.z)); w.w = f2bf(sc * bf2f(w.w));
            hi4[base4 + idx] = w;
        }
    }
}

// accumulate one gathered row-slice into (ax..aw)
#define ACC(vv) { ax += bf2f(vv.x); ay += bf2f(vv.y); az += bf2f(vv.z); aw += bf2f(vv.w); }

// ---- one PLANE pass of a hop: zout = dd^2 * (z_self + sum_s z_s) on a 4MB plane ----
// Block = 320 threads = 64 nodes x 5 lanes (one ushort4 each; 40B rows).
__global__ void __launch_bounds__(320)
gatherP_kernel(const unsigned short* __restrict__ zin, unsigned short* __restrict__ zout,
               const int* __restrict__ rowptr, const int* __restrict__ srcs,
               const float* __restrict__ dis, int n) {
    int tid = threadIdx.x;
    int node = blockIdx.x * 64 + tid / 5;
    int ch = tid - (tid / 5) * 5;
    if (node >= n) return;
    const ushort4* zi = (const ushort4*)zin;
    ushort4 sv = zi[(size_t)node * 5 + ch];
    float ax = bf2f(sv.x), ay = bf2f(sv.y), az = bf2f(sv.z), aw = bf2f(sv.w);
    int beg = rowptr[node], end = rowptr[node + 1];
    int e = beg;
    for (; e + 8 <= end; e += 8) {
        int s0 = srcs[e + 0], s1 = srcs[e + 1], s2 = srcs[e + 2], s3 = srcs[e + 3];
        int s4 = srcs[e + 4], s5 = srcs[e + 5], s6 = srcs[e + 6], s7 = srcs[e + 7];
        ushort4 v0 = zi[(size_t)s0 * 5 + ch];
        ushort4 v1 = zi[(size_t)s1 * 5 + ch];
        ushort4 v2 = zi[(size_t)s2 * 5 + ch];
        ushort4 v3 = zi[(size_t)s3 * 5 + ch];
        ushort4 v4 = zi[(size_t)s4 * 5 + ch];
        ushort4 v5 = zi[(size_t)s5 * 5 + ch];
        ushort4 v6 = zi[(size_t)s6 * 5 + ch];
        ushort4 v7 = zi[(size_t)s7 * 5 + ch];
        ACC(v0) ACC(v1) ACC(v2) ACC(v3) ACC(v4) ACC(v5) ACC(v6) ACC(v7)
    }
    for (; e + 4 <= end; e += 4) {
        int s0 = srcs[e + 0], s1 = srcs[e + 1], s2 = srcs[e + 2], s3 = srcs[e + 3];
        ushort4 v0 = zi[(size_t)s0 * 5 + ch];
        ushort4 v1 = zi[(size_t)s1 * 5 + ch];
        ushort4 v2 = zi[(size_t)s2 * 5 + ch];
        ushort4 v3 = zi[(size_t)s3 * 5 + ch];
        ACC(v0) ACC(v1) ACC(v2) ACC(v3)
    }
    for (; e < end; ++e) {
        ushort4 vv = zi[(size_t)srcs[e] * 5 + ch];
        ACC(vv)
    }
    float dd = dis[node];
    float sc = dd * dd;
    ushort4 o;
    o.x = f2bf(ax * sc); o.y = f2bf(ay * sc); o.z = f2bf(az * sc); o.w = f2bf(aw * sc);
    ((ushort4*)zout)[(size_t)node * 5 + ch] = o;
}

// ---- final hop (scale dd) fused with bias + log_softmax; reads both planes ----
__global__ void __launch_bounds__(320)
gatherZ_lsm_kernel(const unsigned short* __restrict__ zlo, const unsigned short* __restrict__ zhi,
                   const float* __restrict__ b, float* __restrict__ out,
                   const int* __restrict__ rowptr, const int* __restrict__ srcs,
                   const float* __restrict__ dis, int n) {
    __shared__ float sY[32 * C];
    __shared__ float sb[C];
    int tid = threadIdx.x;
    if (tid < C) sb[tid] = b[tid];
    int ndb = tid / 10;
    int ch = tid - ndb * 10;
    int node = blockIdx.x * 32 + ndb;
    if (node < n) {
        const ushort4* zi = (ch < 5) ? (const ushort4*)zlo : (const ushort4*)zhi;
        int cc = (ch < 5) ? ch : ch - 5;
        ushort4 sv = zi[(size_t)node * 5 + cc];
        float ax = bf2f(sv.x), ay = bf2f(sv.y), az = bf2f(sv.z), aw = bf2f(sv.w);
        int beg = rowptr[node], end = rowptr[node + 1];
        int e = beg;
        for (; e + 8 <= end; e += 8) {
            int s0 = srcs[e + 0], s1 = srcs[e + 1], s2 = srcs[e + 2], s3 = srcs[e + 3];
            int s4 = srcs[e + 4], s5 = srcs[e + 5], s6 = srcs[e + 6], s7 = srcs[e + 7];
            ushort4 v0 = zi[(size_t)s0 * 5 + cc];
            ushort4 v1 = zi[(size_t)s1 * 5 + cc];
            ushort4 v2 = zi[(size_t)s2 * 5 + cc];
            ushort4 v3 = zi[(size_t)s3 * 5 + cc];
            ushort4 v4 = zi[(size_t)s4 * 5 + cc];
            ushort4 v5 = zi[(size_t)s5 * 5 + cc];
            ushort4 v6 = zi[(size_t)s6 * 5 + cc];
            ushort4 v7 = zi[(size_t)s7 * 5 + cc];
            ACC(v0) ACC(v1) ACC(v2) ACC(v3) ACC(v4) ACC(v5) ACC(v6) ACC(v7)
        }
        for (; e + 4 <= end; e += 4) {
            int s0 = srcs[e + 0], s1 = srcs[e + 1], s2 = srcs[e + 2], s3 = srcs[e + 3];
            ushort4 v0 = zi[(size_t)s0 * 5 + cc];
            ushort4 v1 = zi[(size_t)s1 * 5 + cc];
            ushort4 v2 = zi[(size_t)s2 * 5 + cc];
            ushort4 v3 = zi[(size_t)s3 * 5 + cc];
            ACC(v0) ACC(v1) ACC(v2) ACC(v3)
        }
        for (; e < end; ++e) {
            ushort4 vv = zi[(size_t)srcs[e] * 5 + cc];
            ACC(vv)
        }
        float dd = dis[node];
        // sY cols: ch<5 -> cols ch*4.. (0..19); ch>=5 -> cols 20..39 in order
        ((float4*)sY)[tid] = make_float4(ax * dd, ay * dd, az * dd, aw * dd);
    }
    __syncthreads();
    if (tid < 256) {
        int nd = tid >> 3;
        int node2 = blockIdx.x * 32 + nd;
        if (node2 < n) {
            int cg = (tid & 7) * 5;
            float a5[5];
#pragma unroll
            for (int j = 0; j < 5; ++j) a5[j] = sY[nd * C + cg + j] + sb[cg + j];
            float m = a5[0];
#pragma unroll
            for (int j = 1; j < 5; ++j) m = fmaxf(m, a5[j]);
#pragma unroll
            for (int off = 1; off < 8; off <<= 1) m = fmaxf(m, __shfl_xor(m, off, 8));
            float ssum = 0.0f;
#pragma unroll
            for (int j = 0; j < 5; ++j) ssum += __expf(a5[j] - m);
#pragma unroll
            for (int off = 1; off < 8; off <<= 1) ssum += __shfl_xor(ssum, off, 8);
            float ls = logf(ssum) + m;
            float* o = out + (size_t)node2 * C + cg;
#pragma unroll
            for (int j = 0; j < 5; ++j) o[j] = a5[j] - ls;
        }
    }
}

extern "C" void kernel_launch(void* const* d_in, const int* in_sizes, int n_in,
                              void* d_out, int out_size, void* d_ws, size_t ws_size,
                              hipStream_t stream) {
    const float* x  = (const float*)d_in[0];
    const int*   ei = (const int*)d_in[1];   // [2, E] flat: row0 = src, row1 = dst
    const float* W  = (const float*)d_in[2]; // [D, C] row-major
    const float* b  = (const float*)d_in[3];
    float* out = (float*)d_out;

    const int N = in_sizes[0] / D;
    const int E = in_sizes[1] / 2;
    const int* src = ei;
    const int* dst = ei + E;
    const int nbkt = (N + 255) >> BSH;       // 391 for N=100000 (<= NBKT_MAX)

    // Workspace: dis | rowptr | btot | bbase | M | ebuf | srcs | 4 z-planes (4MB each)
    size_t npad = ((size_t)N + 256) & ~(size_t)255;
    size_t epad = ((size_t)E + 255) & ~(size_t)255;
    char* p = (char*)d_ws;
    float* dis    = (float*)p;  p += npad * 4;
    int*   rowptr = (int*)p;    p += npad * 4;
    int*   btot   = (int*)p;    p += NBKT_MAX * 4;
    int*   bbase  = (int*)p;    p += (NBKT_MAX + 1) * 4;
    int*   M      = (int*)p;    p += (size_t)NBKT_MAX * NBH * 4;
    int*   ebuf   = (int*)p;    p += epad * 4;
    int*   srcs   = (int*)p;    p += epad * 4;
    size_t plane = (((size_t)N * 20 * 2) + 255) & ~(size_t)255;   // 40B rows
    unsigned short* z0lo = (unsigned short*)p;  p += plane;
    unsigned short* z0hi = (unsigned short*)p;  p += plane;
    unsigned short* z1lo = (unsigned short*)p;  p += plane;
    unsigned short* z1hi = (unsigned short*)p;

    const int TB = 256;
    int ntile = (N + 15) / 16;               // 6250
    int nb_p = (ntile + 3) / 4;              // 1563 proj blocks (4 waves x 16 rows)

    // ---- CSR build + projection (planar y0) ----
    hist_proj_kernel<<<NBH + nb_p, TB, 0, stream>>>(dst, M, E, x, W, z0lo, z0hi, N, nbkt);
    scanM_kernel<<<nbkt, NBH, 0, stream>>>(M, btot, nbkt);
    scanB_kernel<<<1, 512, 0, stream>>>(btot, bbase, rowptr, nbkt, N, E);
    part_kernel<<<NBH, TB, 0, stream>>>(src, dst, M, bbase, ebuf, E, nbkt);
    bucket_csr_kernel<<<nbkt, TB, 0, stream>>>(ebuf, bbase, rowptr, dis, srcs, z0lo, z0hi, N);

    // ---- hops 1-2: per-plane passes (4MB working set, per-XCD L2-resident) ----
    int nb_g = (N + 63) / 64;
    gatherP_kernel<<<nb_g, 320, 0, stream>>>(z0lo, z1lo, rowptr, srcs, dis, N);
    gatherP_kernel<<<nb_g, 320, 0, stream>>>(z0hi, z1hi, rowptr, srcs, dis, N);
    gatherP_kernel<<<nb_g, 320, 0, stream>>>(z1lo, z0lo, rowptr, srcs, dis, N);
    gatherP_kernel<<<nb_g, 320, 0, stream>>>(z1hi, z0hi, rowptr, srcs, dis, N);

    // ---- hop 3 fused with bias + log_softmax (reads both planes) ----
    int nb_l = (N + 31) / 32;
    gatherZ_lsm_kernel<<<nb_l, 320, 0, stream>>>(z0lo, z0hi, b, out, rowptr, srcs, dis, N);
}

// Round 13
// 165.783 us; speedup vs baseline: 1.2126x; 1.2126x over previous
//
#include <hip/hip_runtime.h>

#define D 128
#define C 40
#define NBH 512        // blocks participating in hist/partition (also scanM width)
#define BSH 8          // bucket = dst >> 8  (256 nodes per bucket)
#define NBKT_MAX 512
#define EPB 3136       // max edges per partition block (E/NBH=3125 rounded up)
#define ZS 16          // z row stride in ushort4 units (16*8B = 128B, one L2 line)

typedef __attribute__((ext_vector_type(8))) short s8v;
typedef __attribute__((ext_vector_type(4))) float f4v;

// bf16 <-> f32 (raw ushort storage; f2bf = round-to-nearest-even)
__device__ __forceinline__ float bf2f(unsigned short u) {
    union { unsigned int i; float f; } v; v.i = ((unsigned int)u) << 16; return v.f;
}
__device__ __forceinline__ unsigned short f2bf(float f) {
    unsigned int x = __float_as_uint(f);
    unsigned int r = (x + 0x7FFFu + ((x >> 16) & 1u)) >> 16;
    return (unsigned short)r;
}

// ---- K1: merged LDS-histogram (512 blocks, chunked) || MFMA projection y0 = X W ----
__global__ void hist_proj_kernel(const int* __restrict__ dst, int* __restrict__ M, int E,
                                 const float* __restrict__ x, const float* __restrict__ W,
                                 unsigned short* __restrict__ y, int n, int nbkt) {
    __shared__ int shist[NBKT_MAX];      // 2 KB (hist role only)
    int bid = blockIdx.x, tid = threadIdx.x;
    int role, sub;  // role 1 = hist, 0 = proj
    if (bid < 2 * NBH) { role = bid & 1; sub = bid >> 1; }
    else { role = 0; sub = bid - NBH; }

    if (role == 1) {
        for (int t = tid; t < nbkt; t += 256) shist[t] = 0;
        __syncthreads();
        int chunk = (E + NBH - 1) / NBH;
        int base = sub * chunk;
        int lim = min(E, base + chunk);
        for (int e = base + tid; e < lim; e += 256)
            atomicAdd(&shist[dst[e] >> BSH], 1);
        __syncthreads();
        for (int t = tid; t < nbkt; t += 256) M[t * NBH + sub] = shist[t];
        return;
    }

    // ---- projection role: MFMA 16x16x32 bf16, 16 rows per wave, W in registers ----
    int wid = tid >> 6;
    int lane = tid & 63;
    int tile = sub * 4 + wid;               // 16-row tile
    if (tile * 16 >= n) return;
    int r = lane & 15;
    int kg = lane >> 4;                     // 0..3

    s8v bfrag[3][4];
#pragma unroll
    for (int ct = 0; ct < 3; ++ct) {
        int col = ct * 16 + r;
#pragma unroll
        for (int ks = 0; ks < 4; ++ks) {
            s8v f;
#pragma unroll
            for (int j = 0; j < 8; ++j) {
                int k = ks * 32 + kg * 8 + j;
                float wv = (col < C) ? W[k * C + col] : 0.0f;
                f[j] = (short)f2bf(wv);
            }
            bfrag[ct][ks] = f;
        }
    }

    f4v acc0 = {0.f, 0.f, 0.f, 0.f};
    f4v acc1 = {0.f, 0.f, 0.f, 0.f};
    f4v acc2 = {0.f, 0.f, 0.f, 0.f};
    int row = tile * 16 + r;
    const float4* xrow = (const float4*)(x + (size_t)row * D);
#pragma unroll
    for (int ks = 0; ks < 4; ++ks) {
        int kb = ks * 32 + kg * 8;
        float4 u0 = xrow[kb >> 2];
        float4 u1 = xrow[(kb >> 2) + 1];
        s8v af;
        af[0] = (short)f2bf(u0.x); af[1] = (short)f2bf(u0.y);
        af[2] = (short)f2bf(u0.z); af[3] = (short)f2bf(u0.w);
        af[4] = (short)f2bf(u1.x); af[5] = (short)f2bf(u1.y);
        af[6] = (short)f2bf(u1.z); af[7] = (short)f2bf(u1.w);
        acc0 = __builtin_amdgcn_mfma_f32_16x16x32_bf16(af, bfrag[0][ks], acc0, 0, 0, 0);
        acc1 = __builtin_amdgcn_mfma_f32_16x16x32_bf16(af, bfrag[1][ks], acc1, 0, 0, 0);
        acc2 = __builtin_amdgcn_mfma_f32_16x16x32_bf16(af, bfrag[2][ks], acc2, 0, 0, 0);
    }
    // D layout: col = lane&15, row_in_tile = kg*4 + reg. y row stride = ZS*4 ushorts.
#pragma unroll
    for (int rg = 0; rg < 4; ++rg) {
        int orow = tile * 16 + kg * 4 + rg;
        unsigned short* yr = y + (size_t)orow * (ZS * 4);
        yr[r] = f2bf(acc0[rg]);
        yr[16 + r] = f2bf(acc1[rg]);
        if (r < 8) yr[32 + r] = f2bf(acc2[rg]);
    }
}

// ---- K2: exclusive-scan each bucket's row of M (per-block counts); emit totals ----
__global__ void scanM_kernel(int* __restrict__ M, int* __restrict__ btot, int nbkt) {
    __shared__ int s[NBH];
    int b = blockIdx.x, tid = threadIdx.x;
    int v = M[b * NBH + tid];
    s[tid] = v;
    __syncthreads();
    for (int off = 1; off < NBH; off <<= 1) {
        int t = (tid >= off) ? s[tid - off] : 0;
        __syncthreads();
        s[tid] += t;
        __syncthreads();
    }
    M[b * NBH + tid] = s[tid] - v;   // exclusive
    if (tid == NBH - 1) btot[b] = s[tid];
}

// ---- K3: exclusive-scan bucket totals -> bucketBase; seal rowptr[N] ----
__global__ void scanB_kernel(const int* __restrict__ btot, int* __restrict__ bbase,
                             int* __restrict__ rowptr, int nbkt, int n, int E) {
    __shared__ int s[512];
    int tid = threadIdx.x;
    int v = (tid < nbkt) ? btot[tid] : 0;
    s[tid] = v;
    __syncthreads();
    for (int off = 1; off < 512; off <<= 1) {
        int t = (tid >= off) ? s[tid - off] : 0;
        __syncthreads();
        s[tid] += t;
        __syncthreads();
    }
    if (tid < nbkt) bbase[tid] = s[tid] - v;
    if (tid == 0) { bbase[nbkt] = E; rowptr[n] = E; }
}

// ---- K4: partition via LDS counting sort -> coalesced bucket-run writes ----
__global__ void __launch_bounds__(256)
part_kernel(const int* __restrict__ src, const int* __restrict__ dst,
            const int* __restrict__ M, const int* __restrict__ bbase,
            int* __restrict__ ebuf, int E, int nbkt) {
    __shared__ int lhist[NBKT_MAX];
    __shared__ int ls[NBKT_MAX];        // inclusive scan workspace
    __shared__ int lslot[NBKT_MAX];     // LDS slot cursor per bucket
    __shared__ int sdelta[NBKT_MAX];    // gpos = sdelta[bucket] + slot
    __shared__ int sVal[EPB];
    __shared__ int sG[EPB];
    int blk = blockIdx.x, tid = threadIdx.x;
    int chunk = (E + NBH - 1) / NBH;
    int base = blk * chunk;
    int lim = min(E, base + chunk);
    int cnt = lim - base;
    if (cnt <= 0) return;

    for (int t = tid; t < NBKT_MAX; t += 256) lhist[t] = 0;
    __syncthreads();
    for (int e = base + tid; e < lim; e += 256)
        atomicAdd(&lhist[dst[e] >> BSH], 1);
    __syncthreads();
    {
        int i0 = tid, i1 = tid + 256;
        ls[i0] = lhist[i0]; ls[i1] = lhist[i1];
        __syncthreads();
        for (int off = 1; off < 512; off <<= 1) {
            int v0 = (i0 >= off) ? ls[i0 - off] : 0;
            int v1 = (i1 >= off) ? ls[i1 - off] : 0;
            __syncthreads();
            ls[i0] += v0; ls[i1] += v1;
            __syncthreads();
        }
    }
    for (int t = tid; t < nbkt; t += 256) {
        int excl = ls[t] - lhist[t];
        lslot[t] = excl;
        sdelta[t] = bbase[t] + M[t * NBH + blk] - excl;
    }
    __syncthreads();
    for (int e = base + tid; e < lim; e += 256) {
        int d = dst[e];
        int t = d >> BSH;
        int slot = atomicAdd(&lslot[t], 1);
        sVal[slot] = src[e] | ((d & ((1 << BSH) - 1)) << 17);
        sG[slot] = sdelta[t] + slot;
    }
    __syncthreads();
    for (int i = tid; i < cnt; i += 256) ebuf[sG[i]] = sVal[i];
}

// ---- K5: per-bucket CSR build (hist, scan, rank in LDS) + z0 = dis*y0 ----
__global__ void bucket_csr_kernel(const int* __restrict__ ebuf, const int* __restrict__ bbase,
                                  int* __restrict__ rowptr, float* __restrict__ dis,
                                  int* __restrict__ srcs, unsigned short* __restrict__ y, int n) {
    __shared__ int scnt[256];
    __shared__ int s[256];
    __shared__ int sptr[256];
    __shared__ float sdis[256];
    int b = blockIdx.x, tid = threadIdx.x;
    int lo = bbase[b], hi = bbase[b + 1];
    scnt[tid] = 0;
    __syncthreads();
    for (int i = lo + tid; i < hi; i += 256)
        atomicAdd(&scnt[(ebuf[i] >> 17) & 255], 1);
    __syncthreads();
    int v = scnt[tid];
    s[tid] = v;
    __syncthreads();
    for (int off = 1; off < 256; off <<= 1) {
        int t = (tid >= off) ? s[tid - off] : 0;
        __syncthreads();
        s[tid] += t;
        __syncthreads();
    }
    int excl = s[tid] - v;
    int node = b * 256 + tid;
    float dv = rsqrtf(1.0f + (float)v);
    if (node < n) { rowptr[node] = lo + excl; dis[node] = dv; }
    sdis[tid] = dv;
    sptr[tid] = lo + excl;
    __syncthreads();
    for (int i = lo + tid; i < hi; i += 256) {
        int ev = ebuf[i];
        int pos = atomicAdd(&sptr[(ev >> 17) & 255], 1);
        srcs[pos] = ev & 0x1FFFF;
    }
    // epilogue: z0 = dis * y0 for this bucket's nodes (in place, padded rows)
    __syncthreads();
    ushort4* y4 = (ushort4*)y;
    size_t base4 = (size_t)b * 256 * ZS;
    for (int idx = tid; idx < 256 * ZS; idx += 256) {
        int ch = idx & (ZS - 1);
        int node2 = b * 256 + (idx >> 4);
        if (ch < 10 && node2 < n) {
            ushort4 u = y4[base4 + idx];
            float sc = sdis[idx >> 4];
            u.x = f2bf(sc * bf2f(u.x)); u.y = f2bf(sc * bf2f(u.y));
            u.z = f2bf(sc * bf2f(u.z)); u.w = f2bf(sc * bf2f(u.w));
            y4[base4 + idx] = u;
        }
    }
}

// accumulate one gathered row into (ax..aw)
#define ACC(vv) { ax += bf2f(vv.x); ay += bf2f(vv.y); az += bf2f(vv.z); aw += bf2f(vv.w); }
#define LOAD8ROWS \
    ushort4 v0 = zi[(size_t)sA0 * ZS + ch]; \
    ushort4 v1 = zi[(size_t)sA1 * ZS + ch]; \
    ushort4 v2 = zi[(size_t)sA2 * ZS + ch]; \
    ushort4 v3 = zi[(size_t)sA3 * ZS + ch]; \
    ushort4 v4 = zi[(size_t)sA4 * ZS + ch]; \
    ushort4 v5 = zi[(size_t)sA5 * ZS + ch]; \
    ushort4 v6 = zi[(size_t)sA6 * ZS + ch]; \
    ushort4 v7 = zi[(size_t)sA7 * ZS + ch]; \
    ACC(v0) ACC(v1) ACC(v2) ACC(v3) ACC(v4) ACC(v5) ACC(v6) ACC(v7)

// ---- hop on z (bf16, 128B rows): z' = dd^2 * (z_self + sum_s z_s) ----
// 8-deep unroll + srcs prefetch pipeline (next indices load under current rows).
__global__ void gatherZ_kernel(const unsigned short* __restrict__ zin,
                               unsigned short* __restrict__ zout,
                               const int* __restrict__ rowptr, const int* __restrict__ srcs,
                               const float* __restrict__ dis, int n) {
    int gtid = blockIdx.x * blockDim.x + threadIdx.x;
    int node = gtid / 10;
    int ch = gtid - node * 10;
    if (node >= n) return;
    const ushort4* zi = (const ushort4*)zin;
    ushort4 sv = zi[(size_t)node * ZS + ch];
    float ax = bf2f(sv.x), ay = bf2f(sv.y), az = bf2f(sv.z), aw = bf2f(sv.w);
    int beg = rowptr[node], end = rowptr[node + 1];
    int e = beg;
    if (e + 8 <= end) {
        int sA0 = srcs[e+0], sA1 = srcs[e+1], sA2 = srcs[e+2], sA3 = srcs[e+3];
        int sA4 = srcs[e+4], sA5 = srcs[e+5], sA6 = srcs[e+6], sA7 = srcs[e+7];
        for (; e + 16 <= end; e += 8) {
            int sB0 = srcs[e+8],  sB1 = srcs[e+9],  sB2 = srcs[e+10], sB3 = srcs[e+11];
            int sB4 = srcs[e+12], sB5 = srcs[e+13], sB6 = srcs[e+14], sB7 = srcs[e+15];
            LOAD8ROWS
            sA0 = sB0; sA1 = sB1; sA2 = sB2; sA3 = sB3;
            sA4 = sB4; sA5 = sB5; sA6 = sB6; sA7 = sB7;
        }
        { LOAD8ROWS }
        e += 8;
    }
    for (; e + 4 <= end; e += 4) {
        int s0 = srcs[e + 0], s1 = srcs[e + 1], s2 = srcs[e + 2], s3 = srcs[e + 3];
        ushort4 w0 = zi[(size_t)s0 * ZS + ch];
        ushort4 w1 = zi[(size_t)s1 * ZS + ch];
        ushort4 w2 = zi[(size_t)s2 * ZS + ch];
        ushort4 w3 = zi[(size_t)s3 * ZS + ch];
        ACC(w0) ACC(w1) ACC(w2) ACC(w3)
    }
    for (; e < end; ++e) {
        ushort4 vv = zi[(size_t)srcs[e] * ZS + ch];
        ACC(vv)
    }
    float dd = dis[node];
    float sc = dd * dd;
    ushort4 o;
    o.x = f2bf(ax * sc); o.y = f2bf(ay * sc); o.z = f2bf(az * sc); o.w = f2bf(aw * sc);
    ((ushort4*)zout)[(size_t)node * ZS + ch] = o;
}

// ---- final hop (scale dd) fused with bias + log_softmax. Block = 320. ----
__global__ void __launch_bounds__(320)
gatherZ_lsm_kernel(const unsigned short* __restrict__ zin, const float* __restrict__ b,
                   float* __restrict__ out, const int* __restrict__ rowptr,
                   const int* __restrict__ srcs, const float* __restrict__ dis, int n) {
    __shared__ float sY[32 * C];
    __shared__ float sb[C];
    int tid = threadIdx.x;
    if (tid < C) sb[tid] = b[tid];
    int ndb = tid / 10;
    int ch = tid - ndb * 10;
    int node = blockIdx.x * 32 + ndb;
    if (node < n) {
        const ushort4* zi = (const ushort4*)zin;
        ushort4 sv = zi[(size_t)node * ZS + ch];
        float ax = bf2f(sv.x), ay = bf2f(sv.y), az = bf2f(sv.z), aw = bf2f(sv.w);
        int beg = rowptr[node], end = rowptr[node + 1];
        int e = beg;
        if (e + 8 <= end) {
            int sA0 = srcs[e+0], sA1 = srcs[e+1], sA2 = srcs[e+2], sA3 = srcs[e+3];
            int sA4 = srcs[e+4], sA5 = srcs[e+5], sA6 = srcs[e+6], sA7 = srcs[e+7];
            for (; e + 16 <= end; e += 8) {
                int sB0 = srcs[e+8],  sB1 = srcs[e+9],  sB2 = srcs[e+10], sB3 = srcs[e+11];
                int sB4 = srcs[e+12], sB5 = srcs[e+13], sB6 = srcs[e+14], sB7 = srcs[e+15];
                LOAD8ROWS
                sA0 = sB0; sA1 = sB1; sA2 = sB2; sA3 = sB3;
                sA4 = sB4; sA5 = sB5; sA6 = sB6; sA7 = sB7;
            }
            { LOAD8ROWS }
            e += 8;
        }
        for (; e + 4 <= end; e += 4) {
            int s0 = srcs[e + 0], s1 = srcs[e + 1], s2 = srcs[e + 2], s3 = srcs[e + 3];
            ushort4 w0 = zi[(size_t)s0 * ZS + ch];
            ushort4 w1 = zi[(size_t)s1 * ZS + ch];
            ushort4 w2 = zi[(size_t)s2 * ZS + ch];
            ushort4 w3 = zi[(size_t)s3 * ZS + ch];
            ACC(w0) ACC(w1) ACC(w2) ACC(w3)
        }
        for (; e < end; ++e) {
            ushort4 vv = zi[(size_t)srcs[e] * ZS + ch];
            ACC(vv)
        }
        float dd = dis[node];
        ((float4*)sY)[tid] = make_float4(ax * dd, ay * dd, az * dd, aw * dd);
    }
    __syncthreads();
    if (tid < 256) {
        int nd = tid >> 3;
        int node2 = blockIdx.x * 32 + nd;
        if (node2 < n) {
            int cg = (tid & 7) * 5;
            float a5[5];
#pragma unroll
            for (int j = 0; j < 5; ++j) a5[j] = sY[nd * C + cg + j] + sb[cg + j];
            float m = a5[0];
#pragma unroll
            for (int j = 1; j < 5; ++j) m = fmaxf(m, a5[j]);
#pragma unroll
            for (int off = 1; off < 8; off <<= 1) m = fmaxf(m, __shfl_xor(m, off, 8));
            float ssum = 0.0f;
#pragma unroll
            for (int j = 0; j < 5; ++j) ssum += __expf(a5[j] - m);
#pragma unroll
            for (int off = 1; off < 8; off <<= 1) ssum += __shfl_xor(ssum, off, 8);
            float ls = logf(ssum) + m;
            float* o = out + (size_t)node2 * C + cg;
#pragma unroll
            for (int j = 0; j < 5; ++j) o[j] = a5[j] - ls;
        }
    }
}

extern "C" void kernel_launch(void* const* d_in, const int* in_sizes, int n_in,
                              void* d_out, int out_size, void* d_ws, size_t ws_size,
                              hipStream_t stream) {
    const float* x  = (const float*)d_in[0];
    const int*   ei = (const int*)d_in[1];   // [2, E] flat: row0 = src, row1 = dst
    const float* W  = (const float*)d_in[2]; // [D, C] row-major
    const float* b  = (const float*)d_in[3];
    float* out = (float*)d_out;

    const int N = in_sizes[0] / D;
    const int E = in_sizes[1] / 2;
    const int* src = ei;
    const int* dst = ei + E;
    const int nbkt = (N + 255) >> BSH;       // 391 for N=100000 (<= NBKT_MAX)

    // Workspace: dis | rowptr | btot | bbase | M | ebuf | srcs | zbuf0 | zbuf1
    size_t npad = ((size_t)N + 256) & ~(size_t)255;
    size_t epad = ((size_t)E + 255) & ~(size_t)255;
    char* p = (char*)d_ws;
    float* dis    = (float*)p;  p += npad * 4;
    int*   rowptr = (int*)p;    p += npad * 4;
    int*   btot   = (int*)p;    p += NBKT_MAX * 4;
    int*   bbase  = (int*)p;    p += (NBKT_MAX + 1) * 4;
    int*   M      = (int*)p;    p += (size_t)NBKT_MAX * NBH * 4;
    int*   ebuf   = (int*)p;    p += epad * 4;
    int*   srcs   = (int*)p;    p += epad * 4;
    size_t zpad = (((size_t)N * ZS * 8) + 255) & ~(size_t)255;
    unsigned short* zbuf0 = (unsigned short*)p;  p += zpad;
    unsigned short* zbuf1 = (unsigned short*)p;

    const int TB = 256;
    int ntile = (N + 15) / 16;               // 6250
    int nb_p = (ntile + 3) / 4;              // 1563 proj blocks (4 waves x 16 rows)

    // ---- CSR build + projection ----
    hist_proj_kernel<<<NBH + nb_p, TB, 0, stream>>>(dst, M, E, x, W, zbuf0, N, nbkt);
    scanM_kernel<<<nbkt, NBH, 0, stream>>>(M, btot, nbkt);
    scanB_kernel<<<1, 512, 0, stream>>>(btot, bbase, rowptr, nbkt, N, E);
    part_kernel<<<NBH, TB, 0, stream>>>(src, dst, M, bbase, ebuf, E, nbkt);
    bucket_csr_kernel<<<nbkt, TB, 0, stream>>>(ebuf, bbase, rowptr, dis, srcs, zbuf0, N);

    // ---- K=3 hops on z (bf16); hop 3 fused with bias+log_softmax ----
    int nb_g = ((N * 10) + TB - 1) / TB;
    gatherZ_kernel<<<nb_g, TB, 0, stream>>>(zbuf0, zbuf1, rowptr, srcs, dis, N);
    gatherZ_kernel<<<nb_g, TB, 0, stream>>>(zbuf1, zbuf0, rowptr, srcs, dis, N);
    int nb_l = (N + 31) / 32;
    gatherZ_lsm_kernel<<<nb_l, 320, 0, stream>>>(zbuf0, b, out, rowptr, srcs, dis, N);
}